// Round 1
// baseline (1765.622 us; speedup 1.0000x reference)
//
#include <hip/hip_runtime.h>
#include <hip/hip_bf16.h>

#define N_NODES 50000
#define N_EDGES 800000
#define EMB 64
#define HID 64
#define N_CLASSES 10
#define N_GRAPHS 512

// ---------------- kernels ----------------

// x[node][d] = emb[ids[node]][d], float4-vectorized (16 float4 per row)
__global__ void k_gather_embed(const int* __restrict__ ids,
                               const float* __restrict__ emb,
                               float* __restrict__ x) {
    int t = blockIdx.x * blockDim.x + threadIdx.x;
    if (t >= N_NODES * 16) return;
    int node = t >> 4, j = t & 15;
    const float4* s = (const float4*)(emb + (size_t)ids[node] * EMB);
    ((float4*)(x + (size_t)node * EMB))[j] = s[j];
}

// For each edge e: agg[dst[e]] += x[src[e]]; cnt[dst[e]] += 1
// Thread = (edge, j) with j indexing one float4 of the 64-float row.
__global__ void k_scatter_edges(const int* __restrict__ esrc,
                                const int* __restrict__ edst,
                                const float* __restrict__ x,
                                float* __restrict__ agg,
                                float* __restrict__ cnt) {
    int t = blockIdx.x * blockDim.x + threadIdx.x;
    if (t >= N_EDGES * 16) return;
    int e = t >> 4, j = t & 15;
    int s = esrc[e], d = edst[e];
    float4 v = ((const float4*)(x + (size_t)s * HID))[j];
    float* a = agg + (size_t)d * HID + j * 4;
    atomicAdd(a + 0, v.x);
    atomicAdd(a + 1, v.y);
    atomicAdd(a + 2, v.z);
    atomicAdd(a + 3, v.w);
    if (j == 0) atomicAdd(&cnt[d], 1.0f);
}

// h[i][d] = relu( (agg[i]*inv_cnt) @ Wl + bl + x[i] @ Wr )
// block = 256 threads = 4 nodes x 64 output dims; W matrices staged in LDS.
__global__ void k_sage_linear(const float* __restrict__ agg,
                              const float* __restrict__ cnt,
                              const float* __restrict__ x,
                              const float* __restrict__ Wl,
                              const float* __restrict__ bl,
                              const float* __restrict__ Wr,
                              float* __restrict__ h) {
    __shared__ float sWl[64 * 64];
    __shared__ float sWr[64 * 64];
    for (int i = threadIdx.x; i < 64 * 64; i += 256) {
        sWl[i] = Wl[i];
        sWr[i] = Wr[i];
    }
    __syncthreads();
    int node = blockIdx.x * 4 + (threadIdx.x >> 6);
    int d = threadIdx.x & 63;
    if (node >= N_NODES) return;
    float c = cnt[node];
    float inv = c > 0.0f ? 1.0f / c : 0.0f;
    const float* arow = agg + (size_t)node * HID;
    const float* xrow = x + (size_t)node * HID;
    float acc = bl[d];
#pragma unroll
    for (int k = 0; k < 64; k++) {
        acc += arow[k] * inv * sWl[k * 64 + d] + xrow[k] * sWr[k * 64 + d];
    }
    h[(size_t)node * HID + d] = fmaxf(acc, 0.0f);
}

// psum[batch[i]] += h[i]; pcnt[batch[i]] += 1   (thread per (node, d))
__global__ void k_pool_scatter(const int* __restrict__ batch,
                               const float* __restrict__ h,
                               float* __restrict__ psum,
                               float* __restrict__ pcnt) {
    int t = blockIdx.x * blockDim.x + threadIdx.x;
    if (t >= N_NODES * HID) return;
    int node = t >> 6, d = t & 63;
    int g = batch[node];
    atomicAdd(&psum[(size_t)g * HID + d], h[t]);
    if (d == 0) atomicAdd(&pcnt[g], 1.0f);
}

// out[g][c] = (psum[g]*inv) @ Wout + bout
__global__ void k_output(const float* __restrict__ psum,
                         const float* __restrict__ pcnt,
                         const float* __restrict__ Wout,
                         const float* __restrict__ bout,
                         float* __restrict__ out) {
    int t = blockIdx.x * blockDim.x + threadIdx.x;
    if (t >= N_GRAPHS * N_CLASSES) return;
    int g = t / N_CLASSES, c = t % N_CLASSES;
    float cn = pcnt[g];
    float inv = cn > 0.0f ? 1.0f / cn : 0.0f;
    float acc = bout[c];
#pragma unroll
    for (int k = 0; k < 64; k++) {
        acc += psum[(size_t)g * HID + k] * inv * Wout[k * N_CLASSES + c];
    }
    out[t] = acc;
}

// ---------------- launch ----------------

extern "C" void kernel_launch(void* const* d_in, const int* in_sizes, int n_in,
                              void* d_out, int out_size, void* d_ws, size_t ws_size,
                              hipStream_t stream) {
    const int*   node_ids = (const int*)d_in[0];
    const int*   edge_idx = (const int*)d_in[1];   // [2, E] row-major
    const int*   batch    = (const int*)d_in[2];
    const float* emb      = (const float*)d_in[3];
    const float* Wl0      = (const float*)d_in[4];
    const float* bl0      = (const float*)d_in[5];
    const float* Wr0      = (const float*)d_in[6];
    const float* Wl1      = (const float*)d_in[7];
    const float* bl1      = (const float*)d_in[8];
    const float* Wr1      = (const float*)d_in[9];
    const float* Wout     = (const float*)d_in[10];
    const float* bout     = (const float*)d_in[11];
    float* out = (float*)d_out;

    const int* esrc = edge_idx;
    const int* edst = edge_idx + N_EDGES;

    // workspace layout (floats)
    float* ws = (float*)d_ws;
    float* x0   = ws;                        // N*64
    float* agg  = x0 + (size_t)N_NODES * 64; // N*64
    float* cnt  = agg + (size_t)N_NODES * 64;// N   (contiguous with agg for one memset)
    float* h1   = cnt + N_NODES;             // N*64
    float* psum = h1 + (size_t)N_NODES * 64; // G*64
    float* pcnt = psum + (size_t)N_GRAPHS * 64; // G (contiguous with psum)

    const int BLK = 256;
    size_t agg_cnt_bytes = ((size_t)N_NODES * 64 + N_NODES) * sizeof(float);
    size_t pool_bytes    = ((size_t)N_GRAPHS * 64 + N_GRAPHS) * sizeof(float);

    // 1) embedding gather
    k_gather_embed<<<(N_NODES * 16 + BLK - 1) / BLK, BLK, 0, stream>>>(node_ids, emb, x0);

    // 2) layer 0 aggregate
    hipMemsetAsync(agg, 0, agg_cnt_bytes, stream);
    k_scatter_edges<<<(N_EDGES * 16 + BLK - 1) / BLK, BLK, 0, stream>>>(esrc, edst, x0, agg, cnt);
    k_sage_linear<<<(N_NODES + 3) / 4, BLK, 0, stream>>>(agg, cnt, x0, Wl0, bl0, Wr0, h1);

    // 3) layer 1 aggregate (reuse agg/cnt; h2 goes into x0 buffer)
    hipMemsetAsync(agg, 0, agg_cnt_bytes, stream);
    k_scatter_edges<<<(N_EDGES * 16 + BLK - 1) / BLK, BLK, 0, stream>>>(esrc, edst, h1, agg, cnt);
    k_sage_linear<<<(N_NODES + 3) / 4, BLK, 0, stream>>>(agg, cnt, h1, Wl1, bl1, Wr1, x0);

    // 4) global mean pool + output projection
    hipMemsetAsync(psum, 0, pool_bytes, stream);
    k_pool_scatter<<<(N_NODES * 64 + BLK - 1) / BLK, BLK, 0, stream>>>(batch, x0, psum, pcnt);
    k_output<<<(N_GRAPHS * N_CLASSES + BLK - 1) / BLK, BLK, 0, stream>>>(psum, pcnt, Wout, bout, out);
}

// Round 2
// 722.533 us; speedup vs baseline: 2.4437x; 2.4437x over previous
//
#include <hip/hip_runtime.h>
#include <hip/hip_bf16.h>

#define N_NODES 50000
#define N_EDGES 800000
#define EMB 64
#define HID 64
#define N_CLASSES 10
#define N_GRAPHS 512

// ---------------- kernels ----------------

// x[node][d] = emb[ids[node]][d], float4-vectorized (16 float4 per row)
__global__ void k_gather_embed(const int* __restrict__ ids,
                               const float* __restrict__ emb,
                               float* __restrict__ x) {
    int t = blockIdx.x * blockDim.x + threadIdx.x;
    if (t >= N_NODES * 16) return;
    int node = t >> 4, j = t & 15;
    const float4* s = (const float4*)(emb + (size_t)ids[node] * EMB);
    ((float4*)(x + (size_t)node * EMB))[j] = s[j];
}

// deg[dst[e]]++  (int atomics, one per edge)
__global__ void k_hist(const int* __restrict__ edst, int* __restrict__ deg) {
    int e = blockIdx.x * blockDim.x + threadIdx.x;
    if (e < N_EDGES) atomicAdd(&deg[edst[e]], 1);
}

// exclusive scan of deg[0..N_NODES) -> row_start[0..N_NODES]; single block.
__global__ void k_scan(const int* __restrict__ deg, int* __restrict__ row_start) {
    const int T = 1024;
    const int CHUNK = (N_NODES + T - 1) / T;  // 49
    __shared__ int partial[T];
    int tid = threadIdx.x;
    int base = tid * CHUNK;
    int local = 0;
    for (int i = 0; i < CHUNK; i++) {
        int idx = base + i;
        if (idx < N_NODES) local += deg[idx];
    }
    partial[tid] = local;
    __syncthreads();
    for (int off = 1; off < T; off <<= 1) {
        int v = (tid >= off) ? partial[tid - off] : 0;
        __syncthreads();
        partial[tid] += v;
        __syncthreads();
    }
    int run = (tid > 0) ? partial[tid - 1] : 0;
    for (int i = 0; i < CHUNK; i++) {
        int idx = base + i;
        if (idx < N_NODES) {
            row_start[idx] = run;
            run += deg[idx];
        }
    }
    if (tid == T - 1) row_start[N_NODES] = run;
}

// csr_src[cursor[dst]++] = src  (cursor starts as copy of row_start)
__global__ void k_fill(const int* __restrict__ esrc, const int* __restrict__ edst,
                       int* __restrict__ cursor, int* __restrict__ csr_src) {
    int e = blockIdx.x * blockDim.x + threadIdx.x;
    if (e < N_EDGES) {
        int d = edst[e];
        int pos = atomicAdd(&cursor[d], 1);
        csr_src[pos] = esrc[e];
    }
}

// graph start offsets from sorted batch ids
__global__ void k_gstart(const int* __restrict__ batch, int* __restrict__ gstart) {
    int i = blockIdx.x * blockDim.x + threadIdx.x;
    if (i >= N_NODES) return;
    int b = batch[i];
    int prev = (i == 0) ? -1 : batch[i - 1];
    for (int g = prev + 1; g <= b; g++) gstart[g] = i;
    if (i == N_NODES - 1)
        for (int g = b + 1; g <= N_GRAPHS; g++) gstart[g] = N_NODES;
}

// Fused: mean-aggregate (gather over CSR) + lin_l + lin_r + ReLU.
// One wave (64 lanes) per node; lane = feature dim.
__global__ void k_sage_fused(const int* __restrict__ row_start,
                             const int* __restrict__ csr_src,
                             const float* __restrict__ x,
                             const float* __restrict__ Wl,
                             const float* __restrict__ bl,
                             const float* __restrict__ Wr,
                             float* __restrict__ h) {
    __shared__ float sWl[64 * 64];
    __shared__ float sWr[64 * 64];
    for (int i = threadIdx.x; i < 64 * 64; i += blockDim.x) {
        sWl[i] = Wl[i];
        sWr[i] = Wr[i];
    }
    __syncthreads();
    int wave = (blockIdx.x * blockDim.x + threadIdx.x) >> 6;
    int lane = threadIdx.x & 63;
    if (wave >= N_NODES) return;
    int node = wave;
    int s0 = row_start[node], s1 = row_start[node + 1];
    float sum = 0.0f;
    for (int e = s0; e < s1; e++) {
        int src = csr_src[e];
        sum += x[(size_t)src * HID + lane];
    }
    float inv = (s1 > s0) ? 1.0f / (float)(s1 - s0) : 0.0f;
    float mean = sum * inv;
    float xv = x[(size_t)node * HID + lane];
    float acc = bl[lane];
#pragma unroll
    for (int k = 0; k < 64; k++) {
        float mk = __shfl(mean, k, 64);
        float xk = __shfl(xv, k, 64);
        acc = fmaf(mk, sWl[k * 64 + lane], acc);
        acc = fmaf(xk, sWr[k * 64 + lane], acc);
    }
    h[(size_t)node * HID + lane] = fmaxf(acc, 0.0f);
}

// Fused: segmented mean-pool over sorted batch + output projection.
// One wave per graph; lane = hidden dim.
__global__ void k_pool_out(const int* __restrict__ gstart,
                           const float* __restrict__ h,
                           const float* __restrict__ Wout,
                           const float* __restrict__ bout,
                           float* __restrict__ out) {
    int wave = (blockIdx.x * blockDim.x + threadIdx.x) >> 6;
    int lane = threadIdx.x & 63;
    if (wave >= N_GRAPHS) return;
    int g = wave;
    int s0 = gstart[g], s1 = gstart[g + 1];
    float sum = 0.0f;
    for (int n = s0; n < s1; n++) sum += h[(size_t)n * HID + lane];
    float inv = (s1 > s0) ? 1.0f / (float)(s1 - s0) : 0.0f;
    float pooled = sum * inv;
#pragma unroll
    for (int c = 0; c < N_CLASSES; c++) {
        float v = pooled * Wout[lane * N_CLASSES + c];
#pragma unroll
        for (int off = 32; off > 0; off >>= 1) v += __shfl_down(v, off, 64);
        if (lane == 0) out[(size_t)g * N_CLASSES + c] = v + bout[c];
    }
}

// ---------------- launch ----------------

extern "C" void kernel_launch(void* const* d_in, const int* in_sizes, int n_in,
                              void* d_out, int out_size, void* d_ws, size_t ws_size,
                              hipStream_t stream) {
    const int*   node_ids = (const int*)d_in[0];
    const int*   edge_idx = (const int*)d_in[1];   // [2, E] row-major
    const int*   batch    = (const int*)d_in[2];
    const float* emb      = (const float*)d_in[3];
    const float* Wl0      = (const float*)d_in[4];
    const float* bl0      = (const float*)d_in[5];
    const float* Wr0      = (const float*)d_in[6];
    const float* Wl1      = (const float*)d_in[7];
    const float* bl1      = (const float*)d_in[8];
    const float* Wr1      = (const float*)d_in[9];
    const float* Wout     = (const float*)d_in[10];
    const float* bout     = (const float*)d_in[11];
    float* out = (float*)d_out;

    const int* esrc = edge_idx;
    const int* edst = edge_idx + N_EDGES;

    // workspace layout
    float* ws = (float*)d_ws;
    float* x0       = ws;                               // N*64 floats
    float* h1       = x0 + (size_t)N_NODES * 64;        // N*64 floats
    int*   deg      = (int*)(h1 + (size_t)N_NODES * 64); // N ints
    int*   row_start= deg + N_NODES;                    // N+1 ints
    int*   cursor   = row_start + N_NODES + 1;          // N+1 ints
    int*   csr_src  = cursor + N_NODES + 1;             // E ints
    int*   gstart   = csr_src + N_EDGES;                // G+1 ints

    const int BLK = 256;

    // zero the degree histogram (ws is poisoned 0xAA before every call)
    hipMemsetAsync(deg, 0, N_NODES * sizeof(int), stream);

    // embedding gather (independent of CSR build)
    k_gather_embed<<<(N_NODES * 16 + BLK - 1) / BLK, BLK, 0, stream>>>(node_ids, emb, x0);

    // CSR build (once; reused by both layers)
    k_hist<<<(N_EDGES + BLK - 1) / BLK, BLK, 0, stream>>>(edst, deg);
    k_scan<<<1, 1024, 0, stream>>>(deg, row_start);
    hipMemcpyAsync(cursor, row_start, (N_NODES + 1) * sizeof(int),
                   hipMemcpyDeviceToDevice, stream);
    k_fill<<<(N_EDGES + BLK - 1) / BLK, BLK, 0, stream>>>(esrc, edst, cursor, csr_src);

    // graph boundaries (independent)
    k_gstart<<<(N_NODES + BLK - 1) / BLK, BLK, 0, stream>>>(batch, gstart);

    // two SAGE layers (wave per node)
    const int SAGE_BLOCKS = (N_NODES * 64 + BLK - 1) / BLK;
    k_sage_fused<<<SAGE_BLOCKS, BLK, 0, stream>>>(row_start, csr_src, x0, Wl0, bl0, Wr0, h1);
    k_sage_fused<<<SAGE_BLOCKS, BLK, 0, stream>>>(row_start, csr_src, h1, Wl1, bl1, Wr1, x0);

    // pool + output (wave per graph)
    k_pool_out<<<(N_GRAPHS * 64 + BLK - 1) / BLK, BLK, 0, stream>>>(gstart, x0, Wout, bout, out);
}

// Round 3
// 418.083 us; speedup vs baseline: 4.2231x; 1.7282x over previous
//
#include <hip/hip_runtime.h>
#include <hip/hip_bf16.h>

#define N_NODES 50000
#define N_EDGES 800000
#define EMB 64
#define HID 64
#define N_CLASSES 10
#define N_GRAPHS 512

// ---------------- CSR build ----------------

__global__ void k_hist(const int* __restrict__ edst, int* __restrict__ deg) {
    int e = blockIdx.x * blockDim.x + threadIdx.x;
    if (e < N_EDGES) atomicAdd(&deg[edst[e]], 1);
}

// exclusive scan of deg -> row_start[0..N] and cursor[0..N-1] (copy); 1 block.
__global__ void k_scan(const int* __restrict__ deg, int* __restrict__ row_start,
                       int* __restrict__ cursor) {
    const int T = 1024;
    const int CHUNK = (N_NODES + T - 1) / T;  // 49
    __shared__ int partial[T];
    int tid = threadIdx.x;
    int base = tid * CHUNK;
    int local = 0;
    for (int i = 0; i < CHUNK; i++) {
        int idx = base + i;
        if (idx < N_NODES) local += deg[idx];
    }
    partial[tid] = local;
    __syncthreads();
    for (int off = 1; off < T; off <<= 1) {
        int v = (tid >= off) ? partial[tid - off] : 0;
        __syncthreads();
        partial[tid] += v;
        __syncthreads();
    }
    int run = (tid > 0) ? partial[tid - 1] : 0;
    for (int i = 0; i < CHUNK; i++) {
        int idx = base + i;
        if (idx < N_NODES) {
            row_start[idx] = run;
            cursor[idx] = run;
            run += deg[idx];
        }
    }
    if (tid == T - 1) row_start[N_NODES] = run;
}

__global__ void k_fill(const int* __restrict__ esrc, const int* __restrict__ edst,
                       int* __restrict__ cursor, int* __restrict__ csr_src) {
    int e = blockIdx.x * blockDim.x + threadIdx.x;
    if (e < N_EDGES) {
        int pos = atomicAdd(&cursor[edst[e]], 1);
        csr_src[pos] = esrc[e];
    }
}

__global__ void k_gstart(const int* __restrict__ batch, int* __restrict__ gstart) {
    int i = blockIdx.x * blockDim.x + threadIdx.x;
    if (i >= N_NODES) return;
    int b = batch[i];
    int prev = (i == 0) ? -1 : batch[i - 1];
    for (int g = prev + 1; g <= b; g++) gstart[g] = i;
    if (i == N_NODES - 1)
        for (int g = b + 1; g <= N_GRAPHS; g++) gstart[g] = N_NODES;
}

// ---------------- dense transform: P = X@Wl ; Q(->H) = X@Wr + bl ----------------
// Tile = 64 nodes/block, 256 threads. X row r comes from emb[ids[node]] if ids
// else src[node]. Writes its OWN tile rows only -> in-place Q into H is safe.
#define XPAD 68  // 64+4: keeps 16B alignment, breaks bank aliasing (68%32==4)
__global__ __launch_bounds__(256) void k_xform(
    const int* __restrict__ ids, const float* __restrict__ src,
    const float* __restrict__ Wl, const float* __restrict__ bl,
    const float* __restrict__ Wr,
    float* __restrict__ P, float* __restrict__ Qout) {
    __shared__ float sWl[64 * 64];
    __shared__ float sWr[64 * 64];
    __shared__ float sX[64 * XPAD];
    int t = threadIdx.x;
    int tile = blockIdx.x * 64;
    for (int i = t; i < 64 * 16; i += 256) {
        ((float4*)sWl)[i] = ((const float4*)Wl)[i];
        ((float4*)sWr)[i] = ((const float4*)Wr)[i];
    }
    for (int i = t; i < 64 * 16; i += 256) {
        int r = i >> 4, c = i & 15;
        int node = tile + r;
        float4 v = make_float4(0.f, 0.f, 0.f, 0.f);
        if (node < N_NODES) {
            const float* srow = ids ? (src + (size_t)ids[node] * 64)
                                    : (src + (size_t)node * 64);
            v = ((const float4*)srow)[c];
        }
        *(float4*)&sX[r * XPAD + c * 4] = v;
    }
    __syncthreads();
    int dg = t & 15;   // output dim group (4 dims)
    int ng = t >> 4;   // node subgroup base (nodes ng, ng+16, ng+32, ng+48)
    float accL[4][4], accR[4][4];
#pragma unroll
    for (int i = 0; i < 4; i++)
#pragma unroll
        for (int j = 0; j < 4; j++) { accL[i][j] = 0.f; accR[i][j] = 0.f; }
#pragma unroll 4
    for (int k = 0; k < 64; k++) {
        float4 wl = *(const float4*)&sWl[k * 64 + dg * 4];
        float4 wr = *(const float4*)&sWr[k * 64 + dg * 4];
#pragma unroll
        for (int i = 0; i < 4; i++) {
            float xv = sX[(ng + i * 16) * XPAD + k];
            accL[i][0] = fmaf(xv, wl.x, accL[i][0]);
            accL[i][1] = fmaf(xv, wl.y, accL[i][1]);
            accL[i][2] = fmaf(xv, wl.z, accL[i][2]);
            accL[i][3] = fmaf(xv, wl.w, accL[i][3]);
            accR[i][0] = fmaf(xv, wr.x, accR[i][0]);
            accR[i][1] = fmaf(xv, wr.y, accR[i][1]);
            accR[i][2] = fmaf(xv, wr.z, accR[i][2]);
            accR[i][3] = fmaf(xv, wr.w, accR[i][3]);
        }
    }
    float4 blv = *(const float4*)&bl[dg * 4];
#pragma unroll
    for (int i = 0; i < 4; i++) {
        int node = tile + ng + i * 16;
        if (node < N_NODES) {
            *(float4*)&P[(size_t)node * 64 + dg * 4] =
                make_float4(accL[i][0], accL[i][1], accL[i][2], accL[i][3]);
            *(float4*)&Qout[(size_t)node * 64 + dg * 4] =
                make_float4(accR[i][0] + blv.x, accR[i][1] + blv.y,
                            accR[i][2] + blv.z, accR[i][3] + blv.w);
        }
    }
}

// ---------------- aggregate: H[i] = relu( (sum_j P[j])/deg + H[i] ) ----------------
// One wave per node; lane = dim. Neighbor indices loaded coalesced once per
// 64-chunk, broadcast by shfl; row loads unrolled x4 into independent sums.
__global__ __launch_bounds__(256) void k_aggregate(
    const int* __restrict__ row_start, const int* __restrict__ csr_src,
    const float* __restrict__ P, float* __restrict__ H) {
    int wave = (blockIdx.x * blockDim.x + threadIdx.x) >> 6;
    int lane = threadIdx.x & 63;
    if (wave >= N_NODES) return;
    int node = wave;
    int s0 = row_start[node], s1 = row_start[node + 1];
    float a0 = 0.f, a1 = 0.f, a2 = 0.f, a3 = 0.f;
    for (int base = s0; base < s1; base += 64) {
        int cnt = min(64, s1 - base);
        int idxv = 0;
        if (base + lane < s1) idxv = csr_src[base + lane];
        int j = 0;
        for (; j + 4 <= cnt; j += 4) {
            int n0 = __shfl(idxv, j, 64);
            int n1 = __shfl(idxv, j + 1, 64);
            int n2 = __shfl(idxv, j + 2, 64);
            int n3 = __shfl(idxv, j + 3, 64);
            a0 += P[(size_t)n0 * 64 + lane];
            a1 += P[(size_t)n1 * 64 + lane];
            a2 += P[(size_t)n2 * 64 + lane];
            a3 += P[(size_t)n3 * 64 + lane];
        }
        for (; j < cnt; j++) {
            int n = __shfl(idxv, j, 64);
            a0 += P[(size_t)n * 64 + lane];
        }
    }
    int deg = s1 - s0;
    float inv = (deg > 0) ? 1.0f / (float)deg : 0.0f;
    size_t off = (size_t)node * 64 + lane;
    float q = H[off];
    H[off] = fmaxf(fmaf((a0 + a1) + (a2 + a3), inv, q), 0.0f);
}

// ---------------- pool + output: block (4 waves) per graph ----------------
__global__ __launch_bounds__(256) void k_pool_out(
    const int* __restrict__ gstart, const float* __restrict__ H,
    const float* __restrict__ Wout, const float* __restrict__ bout,
    float* __restrict__ out) {
    __shared__ float part[4][64];
    int g = blockIdx.x;
    int w = threadIdx.x >> 6, lane = threadIdx.x & 63;
    int s0 = gstart[g], s1 = gstart[g + 1];
    float p0 = 0.f, p1 = 0.f;
    for (int n = s0 + w; n < s1; n += 8) {
        p0 += H[(size_t)n * 64 + lane];
        int n2 = n + 4;
        if (n2 < s1) p1 += H[(size_t)n2 * 64 + lane];
    }
    part[w][lane] = p0 + p1;
    __syncthreads();
    if (w == 0) {
        int cnt = s1 - s0;
        float inv = (cnt > 0) ? 1.0f / (float)cnt : 0.0f;
        float pooled = (part[0][lane] + part[1][lane] + part[2][lane] + part[3][lane]) * inv;
#pragma unroll
        for (int c = 0; c < N_CLASSES; c++) {
            float v = pooled * Wout[lane * N_CLASSES + c];
#pragma unroll
            for (int off = 32; off > 0; off >>= 1) v += __shfl_down(v, off, 64);
            if (lane == 0) out[(size_t)g * N_CLASSES + c] = v + bout[c];
        }
    }
}

// ---------------- launch ----------------

extern "C" void kernel_launch(void* const* d_in, const int* in_sizes, int n_in,
                              void* d_out, int out_size, void* d_ws, size_t ws_size,
                              hipStream_t stream) {
    const int*   node_ids = (const int*)d_in[0];
    const int*   edge_idx = (const int*)d_in[1];   // [2, E] row-major
    const int*   batch    = (const int*)d_in[2];
    const float* emb      = (const float*)d_in[3];
    const float* Wl0      = (const float*)d_in[4];
    const float* bl0      = (const float*)d_in[5];
    const float* Wr0      = (const float*)d_in[6];
    const float* Wl1      = (const float*)d_in[7];
    const float* bl1      = (const float*)d_in[8];
    const float* Wr1      = (const float*)d_in[9];
    const float* Wout     = (const float*)d_in[10];
    const float* bout     = (const float*)d_in[11];
    float* out = (float*)d_out;

    const int* esrc = edge_idx;
    const int* edst = edge_idx + N_EDGES;

    // workspace layout
    float* P  = (float*)d_ws;                       // N*64 floats
    float* H  = P + (size_t)N_NODES * 64;           // N*64 floats (Q then h, in place)
    int* deg       = (int*)(H + (size_t)N_NODES * 64);
    int* row_start = deg + N_NODES;                 // N+1
    int* cursor    = row_start + N_NODES + 1;       // N
    int* csr_src   = cursor + N_NODES + 1;          // E
    int* gstart    = csr_src + N_EDGES;             // G+1

    const int BLK = 256;

    hipMemsetAsync(deg, 0, N_NODES * sizeof(int), stream);

    // CSR build (reused by both layers)
    k_hist<<<(N_EDGES + BLK - 1) / BLK, BLK, 0, stream>>>(edst, deg);
    k_scan<<<1, 1024, 0, stream>>>(deg, row_start, cursor);
    k_fill<<<(N_EDGES + BLK - 1) / BLK, BLK, 0, stream>>>(esrc, edst, cursor, csr_src);
    k_gstart<<<(N_NODES + BLK - 1) / BLK, BLK, 0, stream>>>(batch, gstart);

    const int XFORM_BLOCKS = (N_NODES + 63) / 64;
    const int AGG_BLOCKS   = (N_NODES * 64 + BLK - 1) / BLK;

    // layer 0 (embedding gather fused into xform staging)
    k_xform<<<XFORM_BLOCKS, BLK, 0, stream>>>(node_ids, emb, Wl0, bl0, Wr0, P, H);
    k_aggregate<<<AGG_BLOCKS, BLK, 0, stream>>>(row_start, csr_src, P, H);

    // layer 1 (reads H, writes P and Q->H in place per tile)
    k_xform<<<XFORM_BLOCKS, BLK, 0, stream>>>(nullptr, H, Wl1, bl1, Wr1, P, H);
    k_aggregate<<<AGG_BLOCKS, BLK, 0, stream>>>(row_start, csr_src, P, H);

    // pool + output
    k_pool_out<<<N_GRAPHS, BLK, 0, stream>>>(gstart, H, Wout, bout, out);
}

// Round 4
// 293.685 us; speedup vs baseline: 6.0120x; 1.4236x over previous
//
#include <hip/hip_runtime.h>
#include <hip/hip_bf16.h>

#define N_NODES 50000
#define N_EDGES 800000
#define EMB 64
#define HID 64
#define N_CLASSES 10
#define N_GRAPHS 512

#define SCAN_BLK 256
#define SCAN_NB ((N_NODES + SCAN_BLK - 1) / SCAN_BLK)   // 196

// ---------------- CSR build ----------------

__global__ void k_hist(const int* __restrict__ edst, int* __restrict__ deg) {
    int e = blockIdx.x * blockDim.x + threadIdx.x;
    if (e < N_EDGES) atomicAdd(&deg[edst[e]], 1);
}

// phase 1: per-block exclusive scan; excl[i] = local exclusive, bsum[b] = block total
__global__ void k_scan_local(const int* __restrict__ deg,
                             int* __restrict__ excl, int* __restrict__ bsum) {
    __shared__ int tmp[SCAN_BLK];
    int tid = threadIdx.x;
    int i = blockIdx.x * SCAN_BLK + tid;
    int v = (i < N_NODES) ? deg[i] : 0;
    tmp[tid] = v;
    __syncthreads();
    for (int off = 1; off < SCAN_BLK; off <<= 1) {
        int t = (tid >= off) ? tmp[tid - off] : 0;
        __syncthreads();
        tmp[tid] += t;
        __syncthreads();
    }
    if (i < N_NODES) excl[i] = tmp[tid] - v;
    if (tid == SCAN_BLK - 1) bsum[blockIdx.x] = tmp[tid];
}

// phase 2: exclusive scan of the 196 block sums (single small block)
__global__ void k_scan_bsum(const int* __restrict__ bsum, int* __restrict__ boff) {
    __shared__ int tmp[256];
    int tid = threadIdx.x;
    int v = (tid < SCAN_NB) ? bsum[tid] : 0;
    tmp[tid] = v;
    __syncthreads();
    for (int off = 1; off < 256; off <<= 1) {
        int t = (tid >= off) ? tmp[tid - off] : 0;
        __syncthreads();
        tmp[tid] += t;
        __syncthreads();
    }
    if (tid < SCAN_NB) boff[tid] = tmp[tid] - v;
}

// phase 3: add block offsets, write row_start + cursor
__global__ void k_scan_add(const int* __restrict__ excl, const int* __restrict__ boff,
                           int* __restrict__ row_start, int* __restrict__ cursor) {
    int i = blockIdx.x * SCAN_BLK + threadIdx.x;
    if (i < N_NODES) {
        int v = excl[i] + boff[blockIdx.x];
        row_start[i] = v;
        cursor[i] = v;
    }
    if (i == 0) row_start[N_NODES] = N_EDGES;   // total degree is constant
}

__global__ void k_fill(const int* __restrict__ esrc, const int* __restrict__ edst,
                       int* __restrict__ cursor, int* __restrict__ csr_src) {
    int e = blockIdx.x * blockDim.x + threadIdx.x;
    if (e < N_EDGES) {
        int pos = atomicAdd(&cursor[edst[e]], 1);
        csr_src[pos] = esrc[e];
    }
}

__global__ void k_gstart(const int* __restrict__ batch, int* __restrict__ gstart) {
    int i = blockIdx.x * blockDim.x + threadIdx.x;
    if (i >= N_NODES) return;
    int b = batch[i];
    int prev = (i == 0) ? -1 : batch[i - 1];
    for (int g = prev + 1; g <= b; g++) gstart[g] = i;
    if (i == N_NODES - 1)
        for (int g = b + 1; g <= N_GRAPHS; g++) gstart[g] = N_NODES;
}

// ---------------- dense transform: P = X@Wl ; Q(->H) = X@Wr + bl ----------------
#define XPAD 68
__global__ __launch_bounds__(256) void k_xform(
    const int* __restrict__ ids, const float* __restrict__ src,
    const float* __restrict__ Wl, const float* __restrict__ bl,
    const float* __restrict__ Wr,
    float* __restrict__ P, float* __restrict__ Qout) {
    __shared__ float sWl[64 * 64];
    __shared__ float sWr[64 * 64];
    __shared__ float sX[64 * XPAD];
    int t = threadIdx.x;
    int tile = blockIdx.x * 64;
    for (int i = t; i < 64 * 16; i += 256) {
        ((float4*)sWl)[i] = ((const float4*)Wl)[i];
        ((float4*)sWr)[i] = ((const float4*)Wr)[i];
    }
    for (int i = t; i < 64 * 16; i += 256) {
        int r = i >> 4, c = i & 15;
        int node = tile + r;
        float4 v = make_float4(0.f, 0.f, 0.f, 0.f);
        if (node < N_NODES) {
            const float* srow = ids ? (src + (size_t)ids[node] * 64)
                                    : (src + (size_t)node * 64);
            v = ((const float4*)srow)[c];
        }
        *(float4*)&sX[r * XPAD + c * 4] = v;
    }
    __syncthreads();
    int dg = t & 15;
    int ng = t >> 4;
    float accL[4][4], accR[4][4];
#pragma unroll
    for (int i = 0; i < 4; i++)
#pragma unroll
        for (int j = 0; j < 4; j++) { accL[i][j] = 0.f; accR[i][j] = 0.f; }
#pragma unroll 4
    for (int k = 0; k < 64; k++) {
        float4 wl = *(const float4*)&sWl[k * 64 + dg * 4];
        float4 wr = *(const float4*)&sWr[k * 64 + dg * 4];
#pragma unroll
        for (int i = 0; i < 4; i++) {
            float xv = sX[(ng + i * 16) * XPAD + k];
            accL[i][0] = fmaf(xv, wl.x, accL[i][0]);
            accL[i][1] = fmaf(xv, wl.y, accL[i][1]);
            accL[i][2] = fmaf(xv, wl.z, accL[i][2]);
            accL[i][3] = fmaf(xv, wl.w, accL[i][3]);
            accR[i][0] = fmaf(xv, wr.x, accR[i][0]);
            accR[i][1] = fmaf(xv, wr.y, accR[i][1]);
            accR[i][2] = fmaf(xv, wr.z, accR[i][2]);
            accR[i][3] = fmaf(xv, wr.w, accR[i][3]);
        }
    }
    float4 blv = *(const float4*)&bl[dg * 4];
#pragma unroll
    for (int i = 0; i < 4; i++) {
        int node = tile + ng + i * 16;
        if (node < N_NODES) {
            *(float4*)&P[(size_t)node * 64 + dg * 4] =
                make_float4(accL[i][0], accL[i][1], accL[i][2], accL[i][3]);
            *(float4*)&Qout[(size_t)node * 64 + dg * 4] =
                make_float4(accR[i][0] + blv.x, accR[i][1] + blv.y,
                            accR[i][2] + blv.z, accR[i][3] + blv.w);
        }
    }
}

// ---------------- aggregate: H[i] = relu( (sum_j P[j])/deg + H[i] ) ----------------
// Quarter-wave (16 lanes) per node; lane = one float4 of the row. 4-deep unroll
// -> 4 outstanding 16B loads/lane, 16 neighbor rows in flight per wave.
__global__ __launch_bounds__(256) void k_aggregate(
    const int* __restrict__ row_start, const int* __restrict__ csr_src,
    const float* __restrict__ P, float* __restrict__ H) {
    int tid = blockIdx.x * blockDim.x + threadIdx.x;
    int node = tid >> 4;
    if (node >= N_NODES) return;
    int sl = tid & 15;                       // float4 slot
    int lane = threadIdx.x & 63;
    int sub16 = lane & 48;                   // base lane of this quarter-wave
    int s0 = row_start[node], s1 = row_start[node + 1];
    float a0x=0.f,a0y=0.f,a0z=0.f,a0w=0.f;
    float a1x=0.f,a1y=0.f,a1z=0.f,a1w=0.f;
    float a2x=0.f,a2y=0.f,a2z=0.f,a2w=0.f;
    float a3x=0.f,a3y=0.f,a3z=0.f,a3w=0.f;
    for (int base = s0; base < s1; base += 16) {
        int cnt = min(16, s1 - base);
        int idxv = 0;
        if (base + sl < s1) idxv = csr_src[base + sl];
        int j = 0;
        for (; j + 4 <= cnt; j += 4) {
            int n0 = __shfl(idxv, sub16 + j, 64);
            int n1 = __shfl(idxv, sub16 + j + 1, 64);
            int n2 = __shfl(idxv, sub16 + j + 2, 64);
            int n3 = __shfl(idxv, sub16 + j + 3, 64);
            float4 v0 = ((const float4*)(P + (size_t)n0 * 64))[sl];
            float4 v1 = ((const float4*)(P + (size_t)n1 * 64))[sl];
            float4 v2 = ((const float4*)(P + (size_t)n2 * 64))[sl];
            float4 v3 = ((const float4*)(P + (size_t)n3 * 64))[sl];
            a0x += v0.x; a0y += v0.y; a0z += v0.z; a0w += v0.w;
            a1x += v1.x; a1y += v1.y; a1z += v1.z; a1w += v1.w;
            a2x += v2.x; a2y += v2.y; a2z += v2.z; a2w += v2.w;
            a3x += v3.x; a3y += v3.y; a3z += v3.z; a3w += v3.w;
        }
        for (; j < cnt; j++) {
            int n = __shfl(idxv, sub16 + j, 64);
            float4 v = ((const float4*)(P + (size_t)n * 64))[sl];
            a0x += v.x; a0y += v.y; a0z += v.z; a0w += v.w;
        }
    }
    int deg = s1 - s0;
    float inv = (deg > 0) ? 1.0f / (float)deg : 0.0f;
    float4 q = ((const float4*)(H + (size_t)node * 64))[sl];
    float4 r;
    r.x = fmaxf(fmaf(a0x + a1x + a2x + a3x, inv, q.x), 0.0f);
    r.y = fmaxf(fmaf(a0y + a1y + a2y + a3y, inv, q.y), 0.0f);
    r.z = fmaxf(fmaf(a0z + a1z + a2z + a3z, inv, q.z), 0.0f);
    r.w = fmaxf(fmaf(a0w + a1w + a2w + a3w, inv, q.w), 0.0f);
    ((float4*)(H + (size_t)node * 64))[sl] = r;
}

// ---------------- pool + output: block (4 waves) per graph ----------------
__global__ __launch_bounds__(256) void k_pool_out(
    const int* __restrict__ gstart, const float* __restrict__ H,
    const float* __restrict__ Wout, const float* __restrict__ bout,
    float* __restrict__ out) {
    __shared__ float part[4][64];
    int g = blockIdx.x;
    int w = threadIdx.x >> 6, lane = threadIdx.x & 63;
    int s0 = gstart[g], s1 = gstart[g + 1];
    float p0 = 0.f, p1 = 0.f;
    for (int n = s0 + w; n < s1; n += 8) {
        p0 += H[(size_t)n * 64 + lane];
        int n2 = n + 4;
        if (n2 < s1) p1 += H[(size_t)n2 * 64 + lane];
    }
    part[w][lane] = p0 + p1;
    __syncthreads();
    if (w == 0) {
        int cnt = s1 - s0;
        float inv = (cnt > 0) ? 1.0f / (float)cnt : 0.0f;
        float pooled = (part[0][lane] + part[1][lane] + part[2][lane] + part[3][lane]) * inv;
#pragma unroll
        for (int c = 0; c < N_CLASSES; c++) {
            float v = pooled * Wout[lane * N_CLASSES + c];
#pragma unroll
            for (int off = 32; off > 0; off >>= 1) v += __shfl_down(v, off, 64);
            if (lane == 0) out[(size_t)g * N_CLASSES + c] = v + bout[c];
        }
    }
}

// ---------------- launch ----------------

extern "C" void kernel_launch(void* const* d_in, const int* in_sizes, int n_in,
                              void* d_out, int out_size, void* d_ws, size_t ws_size,
                              hipStream_t stream) {
    const int*   node_ids = (const int*)d_in[0];
    const int*   edge_idx = (const int*)d_in[1];   // [2, E] row-major
    const int*   batch    = (const int*)d_in[2];
    const float* emb      = (const float*)d_in[3];
    const float* Wl0      = (const float*)d_in[4];
    const float* bl0      = (const float*)d_in[5];
    const float* Wr0      = (const float*)d_in[6];
    const float* Wl1      = (const float*)d_in[7];
    const float* bl1      = (const float*)d_in[8];
    const float* Wr1      = (const float*)d_in[9];
    const float* Wout     = (const float*)d_in[10];
    const float* bout     = (const float*)d_in[11];
    float* out = (float*)d_out;

    const int* esrc = edge_idx;
    const int* edst = edge_idx + N_EDGES;

    // workspace layout
    float* P  = (float*)d_ws;                       // N*64 floats
    float* H  = P + (size_t)N_NODES * 64;           // N*64 floats
    int* deg       = (int*)(H + (size_t)N_NODES * 64);
    int* row_start = deg + N_NODES;                 // N+1
    int* cursor    = row_start + N_NODES + 1;       // N
    int* excl      = cursor + N_NODES;              // N
    int* bsum      = excl + N_NODES;                // SCAN_NB
    int* boff      = bsum + SCAN_NB;                // SCAN_NB
    int* csr_src   = boff + SCAN_NB;                // E
    int* gstart    = csr_src + N_EDGES;             // G+1

    const int BLK = 256;

    hipMemsetAsync(deg, 0, N_NODES * sizeof(int), stream);

    // CSR build (reused by both layers)
    k_hist<<<(N_EDGES + BLK - 1) / BLK, BLK, 0, stream>>>(edst, deg);
    k_scan_local<<<SCAN_NB, SCAN_BLK, 0, stream>>>(deg, excl, bsum);
    k_scan_bsum<<<1, 256, 0, stream>>>(bsum, boff);
    k_scan_add<<<SCAN_NB, SCAN_BLK, 0, stream>>>(excl, boff, row_start, cursor);
    k_fill<<<(N_EDGES + BLK - 1) / BLK, BLK, 0, stream>>>(esrc, edst, cursor, csr_src);
    k_gstart<<<(N_NODES + BLK - 1) / BLK, BLK, 0, stream>>>(batch, gstart);

    const int XFORM_BLOCKS = (N_NODES + 63) / 64;
    const int AGG_BLOCKS   = (N_NODES * 16 + BLK - 1) / BLK;

    // layer 0 (embedding gather fused into xform staging)
    k_xform<<<XFORM_BLOCKS, BLK, 0, stream>>>(node_ids, emb, Wl0, bl0, Wr0, P, H);
    k_aggregate<<<AGG_BLOCKS, BLK, 0, stream>>>(row_start, csr_src, P, H);

    // layer 1 (reads H, writes P and Q->H in place per tile)
    k_xform<<<XFORM_BLOCKS, BLK, 0, stream>>>(nullptr, H, Wl1, bl1, Wr1, P, H);
    k_aggregate<<<AGG_BLOCKS, BLK, 0, stream>>>(row_start, csr_src, P, H);

    // pool + output
    k_pool_out<<<N_GRAPHS, BLK, 0, stream>>>(gstart, H, Wout, bout, out);
}

// Round 5
// 246.312 us; speedup vs baseline: 7.1682x; 1.1923x over previous
//
#include <hip/hip_runtime.h>
#include <hip/hip_bf16.h>

#define N_NODES 50000
#define N_EDGES 800000
#define EMB 64
#define HID 64
#define N_CLASSES 10
#define N_GRAPHS 512

#define BKT_SHIFT 7
#define BKT_NODES 128
#define NB_BKT ((N_NODES + BKT_NODES - 1) / BKT_NODES)   // 391
#define EB_CHUNK 8192
#define EB_BLOCKS ((N_EDGES + EB_CHUNK - 1) / EB_CHUNK)  // 98

// ---------------- CSR build: bucket multi-split ----------------

// global bucket histogram via LDS pre-aggregation
__global__ __launch_bounds__(256) void k_bhist(const int* __restrict__ edst,
                                               int* __restrict__ bhist) {
    __shared__ int h[NB_BKT];
    for (int i = threadIdx.x; i < NB_BKT; i += 256) h[i] = 0;
    __syncthreads();
    int base = blockIdx.x * EB_CHUNK;
    int end = min(base + EB_CHUNK, N_EDGES);
    for (int i = base + threadIdx.x; i < end; i += 256)
        atomicAdd(&h[edst[i] >> BKT_SHIFT], 1);
    __syncthreads();
    for (int i = threadIdx.x; i < NB_BKT; i += 256)
        if (h[i]) atomicAdd(&bhist[i], h[i]);
}

// exclusive scan of 391 bucket counts; also seeds bucket_cursor
__global__ void k_bscan(const int* __restrict__ bhist,
                        int* __restrict__ bucket_start,
                        int* __restrict__ bucket_cursor) {
    __shared__ int tmp[512];
    int tid = threadIdx.x;
    int v = (tid < NB_BKT) ? bhist[tid] : 0;
    tmp[tid] = v;
    __syncthreads();
    for (int off = 1; off < 512; off <<= 1) {
        int t = (tid >= off) ? tmp[tid - off] : 0;
        __syncthreads();
        tmp[tid] += t;
        __syncthreads();
    }
    if (tid < NB_BKT) {
        int s = tmp[tid] - v;
        bucket_start[tid] = s;
        bucket_cursor[tid] = s;
    }
    if (tid == 0) bucket_start[NB_BKT] = N_EDGES;
}

// multi-split: write edges into bucket-sorted ebuf, packed (local<<16)|src.
// Each block claims one contiguous run per bucket -> compact writebacks.
__global__ __launch_bounds__(256) void k_bsplit(const int* __restrict__ esrc,
                                                const int* __restrict__ edst,
                                                int* __restrict__ bucket_cursor,
                                                int* __restrict__ ebuf) {
    __shared__ int h[NB_BKT];
    __shared__ int bbase[NB_BKT];
    __shared__ int cur[NB_BKT];
    for (int i = threadIdx.x; i < NB_BKT; i += 256) { h[i] = 0; cur[i] = 0; }
    __syncthreads();
    int base = blockIdx.x * EB_CHUNK;
    int end = min(base + EB_CHUNK, N_EDGES);
    for (int i = base + threadIdx.x; i < end; i += 256)
        atomicAdd(&h[edst[i] >> BKT_SHIFT], 1);
    __syncthreads();
    for (int i = threadIdx.x; i < NB_BKT; i += 256)
        if (h[i]) bbase[i] = atomicAdd(&bucket_cursor[i], h[i]);
    __syncthreads();
    for (int i = base + threadIdx.x; i < end; i += 256) {
        int d = edst[i], s = esrc[i];
        int b = d >> BKT_SHIFT;
        int r = atomicAdd(&cur[b], 1);
        ebuf[bbase[b] + r] = ((d & (BKT_NODES - 1)) << 16) | s;
    }
}

// per-bucket: local node histogram + scan -> row_start; scatter csr_src into
// this bucket's private (L2-local) region.
__global__ __launch_bounds__(256) void k_csr_fill(const int* __restrict__ bucket_start,
                                                  const int* __restrict__ ebuf,
                                                  int* __restrict__ row_start,
                                                  int* __restrict__ csr_src) {
    __shared__ int nhist[BKT_NODES];
    __shared__ int sval[BKT_NODES];
    __shared__ int sexcl[BKT_NODES];
    __shared__ int ncur[BKT_NODES];
    int b = blockIdx.x, tid = threadIdx.x;
    int bs = bucket_start[b], be = bucket_start[b + 1];
    if (tid < BKT_NODES) { nhist[tid] = 0; ncur[tid] = 0; }
    __syncthreads();
    for (int i = bs + tid; i < be; i += 256)
        atomicAdd(&nhist[ebuf[i] >> 16], 1);
    __syncthreads();
    if (tid < BKT_NODES) sval[tid] = nhist[tid];
    __syncthreads();
    for (int off = 1; off < BKT_NODES; off <<= 1) {
        int t = 0;
        if (tid < BKT_NODES && tid >= off) t = nhist[tid - off];
        __syncthreads();
        if (tid < BKT_NODES) nhist[tid] += t;
        __syncthreads();
    }
    if (tid < BKT_NODES) {
        sexcl[tid] = nhist[tid] - sval[tid];
        int node = b * BKT_NODES + tid;
        if (node < N_NODES) row_start[node] = bs + sexcl[tid];
    }
    if (b == 0 && tid == 0) row_start[N_NODES] = N_EDGES;
    __syncthreads();
    for (int i = bs + tid; i < be; i += 256) {
        int p = ebuf[i];
        int l = p >> 16, s = p & 0xFFFF;
        int r = atomicAdd(&ncur[l], 1);
        csr_src[bs + sexcl[l] + r] = s;
    }
}

__global__ void k_gstart(const int* __restrict__ batch, int* __restrict__ gstart) {
    int i = blockIdx.x * blockDim.x + threadIdx.x;
    if (i >= N_NODES) return;
    int b = batch[i];
    int prev = (i == 0) ? -1 : batch[i - 1];
    for (int g = prev + 1; g <= b; g++) gstart[g] = i;
    if (i == N_NODES - 1)
        for (int g = b + 1; g <= N_GRAPHS; g++) gstart[g] = N_NODES;
}

// ---------------- dense transform: P = X@Wl ; Q(->H) = X@Wr + bl ----------------
#define XPAD 68
__global__ __launch_bounds__(256) void k_xform(
    const int* __restrict__ ids, const float* __restrict__ src,
    const float* __restrict__ Wl, const float* __restrict__ bl,
    const float* __restrict__ Wr,
    float* __restrict__ P, float* __restrict__ Qout) {
    __shared__ float sWl[64 * 64];
    __shared__ float sWr[64 * 64];
    __shared__ float sX[64 * XPAD];
    int t = threadIdx.x;
    int tile = blockIdx.x * 64;
    for (int i = t; i < 64 * 16; i += 256) {
        ((float4*)sWl)[i] = ((const float4*)Wl)[i];
        ((float4*)sWr)[i] = ((const float4*)Wr)[i];
    }
    for (int i = t; i < 64 * 16; i += 256) {
        int r = i >> 4, c = i & 15;
        int node = tile + r;
        float4 v = make_float4(0.f, 0.f, 0.f, 0.f);
        if (node < N_NODES) {
            const float* srow = ids ? (src + (size_t)ids[node] * 64)
                                    : (src + (size_t)node * 64);
            v = ((const float4*)srow)[c];
        }
        *(float4*)&sX[r * XPAD + c * 4] = v;
    }
    __syncthreads();
    int dg = t & 15;
    int ng = t >> 4;
    float accL[4][4], accR[4][4];
#pragma unroll
    for (int i = 0; i < 4; i++)
#pragma unroll
        for (int j = 0; j < 4; j++) { accL[i][j] = 0.f; accR[i][j] = 0.f; }
#pragma unroll 4
    for (int k = 0; k < 64; k++) {
        float4 wl = *(const float4*)&sWl[k * 64 + dg * 4];
        float4 wr = *(const float4*)&sWr[k * 64 + dg * 4];
#pragma unroll
        for (int i = 0; i < 4; i++) {
            float xv = sX[(ng + i * 16) * XPAD + k];
            accL[i][0] = fmaf(xv, wl.x, accL[i][0]);
            accL[i][1] = fmaf(xv, wl.y, accL[i][1]);
            accL[i][2] = fmaf(xv, wl.z, accL[i][2]);
            accL[i][3] = fmaf(xv, wl.w, accL[i][3]);
            accR[i][0] = fmaf(xv, wr.x, accR[i][0]);
            accR[i][1] = fmaf(xv, wr.y, accR[i][1]);
            accR[i][2] = fmaf(xv, wr.z, accR[i][2]);
            accR[i][3] = fmaf(xv, wr.w, accR[i][3]);
        }
    }
    float4 blv = *(const float4*)&bl[dg * 4];
#pragma unroll
    for (int i = 0; i < 4; i++) {
        int node = tile + ng + i * 16;
        if (node < N_NODES) {
            *(float4*)&P[(size_t)node * 64 + dg * 4] =
                make_float4(accL[i][0], accL[i][1], accL[i][2], accL[i][3]);
            *(float4*)&Qout[(size_t)node * 64 + dg * 4] =
                make_float4(accR[i][0] + blv.x, accR[i][1] + blv.y,
                            accR[i][2] + blv.z, accR[i][3] + blv.w);
        }
    }
}

// ---------------- aggregate: H[i] = relu( (sum_j P[j])/deg + H[i] ) ----------------
__global__ __launch_bounds__(256) void k_aggregate(
    const int* __restrict__ row_start, const int* __restrict__ csr_src,
    const float* __restrict__ P, float* __restrict__ H) {
    int tid = blockIdx.x * blockDim.x + threadIdx.x;
    int node = tid >> 4;
    if (node >= N_NODES) return;
    int sl = tid & 15;
    int lane = threadIdx.x & 63;
    int sub16 = lane & 48;
    int s0 = row_start[node], s1 = row_start[node + 1];
    float a0x=0.f,a0y=0.f,a0z=0.f,a0w=0.f;
    float a1x=0.f,a1y=0.f,a1z=0.f,a1w=0.f;
    float a2x=0.f,a2y=0.f,a2z=0.f,a2w=0.f;
    float a3x=0.f,a3y=0.f,a3z=0.f,a3w=0.f;
    for (int base = s0; base < s1; base += 16) {
        int cnt = min(16, s1 - base);
        int idxv = 0;
        if (base + sl < s1) idxv = csr_src[base + sl];
        int j = 0;
        for (; j + 4 <= cnt; j += 4) {
            int n0 = __shfl(idxv, sub16 + j, 64);
            int n1 = __shfl(idxv, sub16 + j + 1, 64);
            int n2 = __shfl(idxv, sub16 + j + 2, 64);
            int n3 = __shfl(idxv, sub16 + j + 3, 64);
            float4 v0 = ((const float4*)(P + (size_t)n0 * 64))[sl];
            float4 v1 = ((const float4*)(P + (size_t)n1 * 64))[sl];
            float4 v2 = ((const float4*)(P + (size_t)n2 * 64))[sl];
            float4 v3 = ((const float4*)(P + (size_t)n3 * 64))[sl];
            a0x += v0.x; a0y += v0.y; a0z += v0.z; a0w += v0.w;
            a1x += v1.x; a1y += v1.y; a1z += v1.z; a1w += v1.w;
            a2x += v2.x; a2y += v2.y; a2z += v2.z; a2w += v2.w;
            a3x += v3.x; a3y += v3.y; a3z += v3.z; a3w += v3.w;
        }
        for (; j < cnt; j++) {
            int n = __shfl(idxv, sub16 + j, 64);
            float4 v = ((const float4*)(P + (size_t)n * 64))[sl];
            a0x += v.x; a0y += v.y; a0z += v.z; a0w += v.w;
        }
    }
    int deg = s1 - s0;
    float inv = (deg > 0) ? 1.0f / (float)deg : 0.0f;
    float4 q = ((const float4*)(H + (size_t)node * 64))[sl];
    float4 r;
    r.x = fmaxf(fmaf(a0x + a1x + a2x + a3x, inv, q.x), 0.0f);
    r.y = fmaxf(fmaf(a0y + a1y + a2y + a3y, inv, q.y), 0.0f);
    r.z = fmaxf(fmaf(a0z + a1z + a2z + a3z, inv, q.z), 0.0f);
    r.w = fmaxf(fmaf(a0w + a1w + a2w + a3w, inv, q.w), 0.0f);
    ((float4*)(H + (size_t)node * 64))[sl] = r;
}

// ---------------- pool + output ----------------
__global__ __launch_bounds__(256) void k_pool_out(
    const int* __restrict__ gstart, const float* __restrict__ H,
    const float* __restrict__ Wout, const float* __restrict__ bout,
    float* __restrict__ out) {
    __shared__ float part[4][64];
    int g = blockIdx.x;
    int w = threadIdx.x >> 6, lane = threadIdx.x & 63;
    int s0 = gstart[g], s1 = gstart[g + 1];
    float p0 = 0.f, p1 = 0.f;
    for (int n = s0 + w; n < s1; n += 8) {
        p0 += H[(size_t)n * 64 + lane];
        int n2 = n + 4;
        if (n2 < s1) p1 += H[(size_t)n2 * 64 + lane];
    }
    part[w][lane] = p0 + p1;
    __syncthreads();
    if (w == 0) {
        int cnt = s1 - s0;
        float inv = (cnt > 0) ? 1.0f / (float)cnt : 0.0f;
        float pooled = (part[0][lane] + part[1][lane] + part[2][lane] + part[3][lane]) * inv;
#pragma unroll
        for (int c = 0; c < N_CLASSES; c++) {
            float v = pooled * Wout[lane * N_CLASSES + c];
#pragma unroll
            for (int off = 32; off > 0; off >>= 1) v += __shfl_down(v, off, 64);
            if (lane == 0) out[(size_t)g * N_CLASSES + c] = v + bout[c];
        }
    }
}

// ---------------- launch ----------------

extern "C" void kernel_launch(void* const* d_in, const int* in_sizes, int n_in,
                              void* d_out, int out_size, void* d_ws, size_t ws_size,
                              hipStream_t stream) {
    const int*   node_ids = (const int*)d_in[0];
    const int*   edge_idx = (const int*)d_in[1];   // [2, E] row-major
    const int*   batch    = (const int*)d_in[2];
    const float* emb      = (const float*)d_in[3];
    const float* Wl0      = (const float*)d_in[4];
    const float* bl0      = (const float*)d_in[5];
    const float* Wr0      = (const float*)d_in[6];
    const float* Wl1      = (const float*)d_in[7];
    const float* bl1      = (const float*)d_in[8];
    const float* Wr1      = (const float*)d_in[9];
    const float* Wout     = (const float*)d_in[10];
    const float* bout     = (const float*)d_in[11];
    float* out = (float*)d_out;

    const int* esrc = edge_idx;
    const int* edst = edge_idx + N_EDGES;

    // workspace layout
    float* P  = (float*)d_ws;                       // N*64 floats
    float* H  = P + (size_t)N_NODES * 64;           // N*64 floats
    int* row_start     = (int*)(H + (size_t)N_NODES * 64); // N+1
    int* csr_src       = row_start + N_NODES + 1;   // E
    int* bhist         = csr_src + N_EDGES;         // NB
    int* bucket_start  = bhist + NB_BKT;            // NB+1
    int* bucket_cursor = bucket_start + NB_BKT + 1; // NB
    int* gstart        = bucket_cursor + NB_BKT;    // G+1
    // ebuf (E ints = 3.2 MB) aliases P (12.8 MB): consumed by k_csr_fill
    // before k_xform writes P. Stream-ordered -> safe.
    int* ebuf = (int*)P;

    const int BLK = 256;

    hipMemsetAsync(bhist, 0, NB_BKT * sizeof(int), stream);

    // CSR build (reused by both layers)
    k_bhist<<<EB_BLOCKS, BLK, 0, stream>>>(edst, bhist);
    k_bscan<<<1, 512, 0, stream>>>(bhist, bucket_start, bucket_cursor);
    k_bsplit<<<EB_BLOCKS, BLK, 0, stream>>>(esrc, edst, bucket_cursor, ebuf);
    k_csr_fill<<<NB_BKT, BLK, 0, stream>>>(bucket_start, ebuf, row_start, csr_src);
    k_gstart<<<(N_NODES + BLK - 1) / BLK, BLK, 0, stream>>>(batch, gstart);

    const int XFORM_BLOCKS = (N_NODES + 63) / 64;
    const int AGG_BLOCKS   = (N_NODES * 16 + BLK - 1) / BLK;

    // layer 0 (embedding gather fused into xform staging)
    k_xform<<<XFORM_BLOCKS, BLK, 0, stream>>>(node_ids, emb, Wl0, bl0, Wr0, P, H);
    k_aggregate<<<AGG_BLOCKS, BLK, 0, stream>>>(row_start, csr_src, P, H);

    // layer 1
    k_xform<<<XFORM_BLOCKS, BLK, 0, stream>>>(nullptr, H, Wl1, bl1, Wr1, P, H);
    k_aggregate<<<AGG_BLOCKS, BLK, 0, stream>>>(row_start, csr_src, P, H);

    // pool + output
    k_pool_out<<<N_GRAPHS, BLK, 0, stream>>>(gstart, H, Wout, bout, out);
}

// Round 6
// 239.700 us; speedup vs baseline: 7.3660x; 1.0276x over previous
//
#include <hip/hip_runtime.h>
#include <hip/hip_bf16.h>

#define N_NODES 50000
#define N_EDGES 800000
#define EMB 64
#define HID 64
#define N_CLASSES 10
#define N_GRAPHS 512

#define BKT_SHIFT 7
#define BKT_NODES 128
#define NB_BKT ((N_NODES + BKT_NODES - 1) / BKT_NODES)   // 391
#define EB_CHUNK 8192
#define EB_BLOCKS ((N_EDGES + EB_CHUNK - 1) / EB_CHUNK)  // 98

// ---------------- CSR build: bucket multi-split ----------------

__global__ __launch_bounds__(256) void k_bhist(const int* __restrict__ edst,
                                               int* __restrict__ bhist) {
    __shared__ int h[NB_BKT];
    for (int i = threadIdx.x; i < NB_BKT; i += 256) h[i] = 0;
    __syncthreads();
    int base = blockIdx.x * EB_CHUNK;
    int end = min(base + EB_CHUNK, N_EDGES);
    for (int i = base + threadIdx.x; i < end; i += 256)
        atomicAdd(&h[edst[i] >> BKT_SHIFT], 1);
    __syncthreads();
    for (int i = threadIdx.x; i < NB_BKT; i += 256)
        if (h[i]) atomicAdd(&bhist[i], h[i]);
}

__global__ void k_bscan(const int* __restrict__ bhist,
                        int* __restrict__ bucket_start,
                        int* __restrict__ bucket_cursor) {
    __shared__ int tmp[512];
    int tid = threadIdx.x;
    int v = (tid < NB_BKT) ? bhist[tid] : 0;
    tmp[tid] = v;
    __syncthreads();
    for (int off = 1; off < 512; off <<= 1) {
        int t = (tid >= off) ? tmp[tid - off] : 0;
        __syncthreads();
        tmp[tid] += t;
        __syncthreads();
    }
    if (tid < NB_BKT) {
        int s = tmp[tid] - v;
        bucket_start[tid] = s;
        bucket_cursor[tid] = s;
    }
    if (tid == 0) bucket_start[NB_BKT] = N_EDGES;
}

__global__ __launch_bounds__(256) void k_bsplit(const int* __restrict__ esrc,
                                                const int* __restrict__ edst,
                                                int* __restrict__ bucket_cursor,
                                                int* __restrict__ ebuf) {
    __shared__ int h[NB_BKT];
    __shared__ int bbase[NB_BKT];
    __shared__ int cur[NB_BKT];
    for (int i = threadIdx.x; i < NB_BKT; i += 256) { h[i] = 0; cur[i] = 0; }
    __syncthreads();
    int base = blockIdx.x * EB_CHUNK;
    int end = min(base + EB_CHUNK, N_EDGES);
    for (int i = base + threadIdx.x; i < end; i += 256)
        atomicAdd(&h[edst[i] >> BKT_SHIFT], 1);
    __syncthreads();
    for (int i = threadIdx.x; i < NB_BKT; i += 256)
        if (h[i]) bbase[i] = atomicAdd(&bucket_cursor[i], h[i]);
    __syncthreads();
    for (int i = base + threadIdx.x; i < end; i += 256) {
        int d = edst[i], s = esrc[i];
        int b = d >> BKT_SHIFT;
        int r = atomicAdd(&cur[b], 1);
        ebuf[bbase[b] + r] = ((d & (BKT_NODES - 1)) << 16) | s;
    }
}

// per-bucket: LDS node-histogram + scan -> row_start; scatter ushort csr_src.
__global__ __launch_bounds__(256) void k_csr_fill(const int* __restrict__ bucket_start,
                                                  const int* __restrict__ ebuf,
                                                  int* __restrict__ row_start,
                                                  unsigned short* __restrict__ csr_src) {
    __shared__ int nhist[BKT_NODES];
    __shared__ int sval[BKT_NODES];
    __shared__ int sexcl[BKT_NODES];
    __shared__ int ncur[BKT_NODES];
    int b = blockIdx.x, tid = threadIdx.x;
    int bs = bucket_start[b], be = bucket_start[b + 1];
    if (tid < BKT_NODES) { nhist[tid] = 0; ncur[tid] = 0; }
    __syncthreads();
    for (int i = bs + tid; i < be; i += 256)
        atomicAdd(&nhist[ebuf[i] >> 16], 1);
    __syncthreads();
    if (tid < BKT_NODES) sval[tid] = nhist[tid];
    __syncthreads();
    for (int off = 1; off < BKT_NODES; off <<= 1) {
        int t = 0;
        if (tid < BKT_NODES && tid >= off) t = nhist[tid - off];
        __syncthreads();
        if (tid < BKT_NODES) nhist[tid] += t;
        __syncthreads();
    }
    if (tid < BKT_NODES) {
        sexcl[tid] = nhist[tid] - sval[tid];
        int node = b * BKT_NODES + tid;
        if (node < N_NODES) row_start[node] = bs + sexcl[tid];
    }
    if (b == 0 && tid == 0) row_start[N_NODES] = N_EDGES;
    __syncthreads();
    for (int i = bs + tid; i < be; i += 256) {
        int p = ebuf[i];
        int l = p >> 16, s = p & 0xFFFF;
        int r = atomicAdd(&ncur[l], 1);
        csr_src[bs + sexcl[l] + r] = (unsigned short)s;
    }
}

__global__ void k_gstart(const int* __restrict__ batch, int* __restrict__ gstart) {
    int i = blockIdx.x * blockDim.x + threadIdx.x;
    if (i >= N_NODES) return;
    int b = batch[i];
    int prev = (i == 0) ? -1 : batch[i - 1];
    for (int g = prev + 1; g <= b; g++) gstart[g] = i;
    if (i == N_NODES - 1)
        for (int g = b + 1; g <= N_GRAPHS; g++) gstart[g] = N_NODES;
}

// ---------------- dense transform: P(bf16) = X@Wl ; Q(->H,f32) = X@Wr + bl ----------------
#define XPAD 68
__global__ __launch_bounds__(256) void k_xform(
    const int* __restrict__ ids, const float* __restrict__ src,
    const float* __restrict__ Wl, const float* __restrict__ bl,
    const float* __restrict__ Wr,
    __hip_bfloat16* __restrict__ Pb, float* __restrict__ Qout) {
    __shared__ float sWl[64 * 64];
    __shared__ float sWr[64 * 64];
    __shared__ float sX[64 * XPAD];
    int t = threadIdx.x;
    int tile = blockIdx.x * 64;
    for (int i = t; i < 64 * 16; i += 256) {
        ((float4*)sWl)[i] = ((const float4*)Wl)[i];
        ((float4*)sWr)[i] = ((const float4*)Wr)[i];
    }
    for (int i = t; i < 64 * 16; i += 256) {
        int r = i >> 4, c = i & 15;
        int node = tile + r;
        float4 v = make_float4(0.f, 0.f, 0.f, 0.f);
        if (node < N_NODES) {
            const float* srow = ids ? (src + (size_t)ids[node] * 64)
                                    : (src + (size_t)node * 64);
            v = ((const float4*)srow)[c];
        }
        *(float4*)&sX[r * XPAD + c * 4] = v;
    }
    __syncthreads();
    int dg = t & 15;
    int ng = t >> 4;
    float accL[4][4], accR[4][4];
#pragma unroll
    for (int i = 0; i < 4; i++)
#pragma unroll
        for (int j = 0; j < 4; j++) { accL[i][j] = 0.f; accR[i][j] = 0.f; }
#pragma unroll 4
    for (int k = 0; k < 64; k++) {
        float4 wl = *(const float4*)&sWl[k * 64 + dg * 4];
        float4 wr = *(const float4*)&sWr[k * 64 + dg * 4];
#pragma unroll
        for (int i = 0; i < 4; i++) {
            float xv = sX[(ng + i * 16) * XPAD + k];
            accL[i][0] = fmaf(xv, wl.x, accL[i][0]);
            accL[i][1] = fmaf(xv, wl.y, accL[i][1]);
            accL[i][2] = fmaf(xv, wl.z, accL[i][2]);
            accL[i][3] = fmaf(xv, wl.w, accL[i][3]);
            accR[i][0] = fmaf(xv, wr.x, accR[i][0]);
            accR[i][1] = fmaf(xv, wr.y, accR[i][1]);
            accR[i][2] = fmaf(xv, wr.z, accR[i][2]);
            accR[i][3] = fmaf(xv, wr.w, accR[i][3]);
        }
    }
    float4 blv = *(const float4*)&bl[dg * 4];
#pragma unroll
    for (int i = 0; i < 4; i++) {
        int node = tile + ng + i * 16;
        if (node < N_NODES) {
            union { ushort4 u; __hip_bfloat16 h[4]; } pk;
            pk.h[0] = __float2bfloat16(accL[i][0]);
            pk.h[1] = __float2bfloat16(accL[i][1]);
            pk.h[2] = __float2bfloat16(accL[i][2]);
            pk.h[3] = __float2bfloat16(accL[i][3]);
            *(ushort4*)&Pb[(size_t)node * 64 + dg * 4] = pk.u;
            *(float4*)&Qout[(size_t)node * 64 + dg * 4] =
                make_float4(accR[i][0] + blv.x, accR[i][1] + blv.y,
                            accR[i][2] + blv.z, accR[i][3] + blv.w);
        }
    }
}

// ---------------- aggregate: H[i] = relu( (sum_j Pb[j])/deg + H[i] ) ----------------
// Eighth-wave (8 lanes) per node; lane = 8 bf16 dims (16B). 8 rows in flight
// per lane-group via full-chunk unroll into 4 accumulator sets.
__global__ __launch_bounds__(256) void k_aggregate(
    const int* __restrict__ row_start, const unsigned short* __restrict__ csr_src,
    const __hip_bfloat16* __restrict__ Pb, float* __restrict__ H) {
    int tid = blockIdx.x * blockDim.x + threadIdx.x;
    int node = tid >> 3;
    if (node >= N_NODES) return;
    int sl = tid & 7;                        // 16B slot within the 128B row
    int lane = threadIdx.x & 63;
    int sub8 = lane & 56;                    // base lane of this eighth-wave
    int s0 = row_start[node], s1 = row_start[node + 1];
    float a[4][8];
#pragma unroll
    for (int i = 0; i < 4; i++)
#pragma unroll
        for (int j = 0; j < 8; j++) a[i][j] = 0.f;

#define ACC8(vv, A)                                                            \
    do {                                                                       \
        A[0] += __uint_as_float((vv).x << 16);                                 \
        A[1] += __uint_as_float((vv).x & 0xFFFF0000u);                         \
        A[2] += __uint_as_float((vv).y << 16);                                 \
        A[3] += __uint_as_float((vv).y & 0xFFFF0000u);                         \
        A[4] += __uint_as_float((vv).z << 16);                                 \
        A[5] += __uint_as_float((vv).z & 0xFFFF0000u);                         \
        A[6] += __uint_as_float((vv).w << 16);                                 \
        A[7] += __uint_as_float((vv).w & 0xFFFF0000u);                         \
    } while (0)

    for (int base = s0; base < s1; base += 8) {
        int cnt = min(8, s1 - base);
        int idxv = 0;
        if (base + sl < s1) idxv = csr_src[base + sl];
        if (cnt == 8) {
            int n0 = __shfl(idxv, sub8 + 0, 64);
            int n1 = __shfl(idxv, sub8 + 1, 64);
            int n2 = __shfl(idxv, sub8 + 2, 64);
            int n3 = __shfl(idxv, sub8 + 3, 64);
            int n4 = __shfl(idxv, sub8 + 4, 64);
            int n5 = __shfl(idxv, sub8 + 5, 64);
            int n6 = __shfl(idxv, sub8 + 6, 64);
            int n7 = __shfl(idxv, sub8 + 7, 64);
            uint4 v0 = ((const uint4*)(Pb + (size_t)n0 * 64))[sl];
            uint4 v1 = ((const uint4*)(Pb + (size_t)n1 * 64))[sl];
            uint4 v2 = ((const uint4*)(Pb + (size_t)n2 * 64))[sl];
            uint4 v3 = ((const uint4*)(Pb + (size_t)n3 * 64))[sl];
            uint4 v4 = ((const uint4*)(Pb + (size_t)n4 * 64))[sl];
            uint4 v5 = ((const uint4*)(Pb + (size_t)n5 * 64))[sl];
            uint4 v6 = ((const uint4*)(Pb + (size_t)n6 * 64))[sl];
            uint4 v7 = ((const uint4*)(Pb + (size_t)n7 * 64))[sl];
            ACC8(v0, a[0]); ACC8(v1, a[1]); ACC8(v2, a[2]); ACC8(v3, a[3]);
            ACC8(v4, a[0]); ACC8(v5, a[1]); ACC8(v6, a[2]); ACC8(v7, a[3]);
        } else {
            for (int j = 0; j < cnt; j++) {
                int n = __shfl(idxv, sub8 + j, 64);
                uint4 v = ((const uint4*)(Pb + (size_t)n * 64))[sl];
                ACC8(v, a[j & 3]);
            }
        }
    }
    int deg = s1 - s0;
    float inv = (deg > 0) ? 1.0f / (float)deg : 0.0f;
    size_t off = (size_t)node * 64 + sl * 8;
    float4 q0 = *(const float4*)&H[off];
    float4 q1 = *(const float4*)&H[off + 4];
    float4 r0, r1;
    r0.x = fmaxf(fmaf(a[0][0] + a[1][0] + a[2][0] + a[3][0], inv, q0.x), 0.0f);
    r0.y = fmaxf(fmaf(a[0][1] + a[1][1] + a[2][1] + a[3][1], inv, q0.y), 0.0f);
    r0.z = fmaxf(fmaf(a[0][2] + a[1][2] + a[2][2] + a[3][2], inv, q0.z), 0.0f);
    r0.w = fmaxf(fmaf(a[0][3] + a[1][3] + a[2][3] + a[3][3], inv, q0.w), 0.0f);
    r1.x = fmaxf(fmaf(a[0][4] + a[1][4] + a[2][4] + a[3][4], inv, q1.x), 0.0f);
    r1.y = fmaxf(fmaf(a[0][5] + a[1][5] + a[2][5] + a[3][5], inv, q1.y), 0.0f);
    r1.z = fmaxf(fmaf(a[0][6] + a[1][6] + a[2][6] + a[3][6], inv, q1.z), 0.0f);
    r1.w = fmaxf(fmaf(a[0][7] + a[1][7] + a[2][7] + a[3][7], inv, q1.w), 0.0f);
    *(float4*)&H[off] = r0;
    *(float4*)&H[off + 4] = r1;
#undef ACC8
}

// ---------------- pool + output ----------------
__global__ __launch_bounds__(256) void k_pool_out(
    const int* __restrict__ gstart, const float* __restrict__ H,
    const float* __restrict__ Wout, const float* __restrict__ bout,
    float* __restrict__ out) {
    __shared__ float part[4][64];
    int g = blockIdx.x;
    int w = threadIdx.x >> 6, lane = threadIdx.x & 63;
    int s0 = gstart[g], s1 = gstart[g + 1];
    float p0 = 0.f, p1 = 0.f;
    for (int n = s0 + w; n < s1; n += 8) {
        p0 += H[(size_t)n * 64 + lane];
        int n2 = n + 4;
        if (n2 < s1) p1 += H[(size_t)n2 * 64 + lane];
    }
    part[w][lane] = p0 + p1;
    __syncthreads();
    if (w == 0) {
        int cnt = s1 - s0;
        float inv = (cnt > 0) ? 1.0f / (float)cnt : 0.0f;
        float pooled = (part[0][lane] + part[1][lane] + part[2][lane] + part[3][lane]) * inv;
#pragma unroll
        for (int c = 0; c < N_CLASSES; c++) {
            float v = pooled * Wout[lane * N_CLASSES + c];
#pragma unroll
            for (int off = 32; off > 0; off >>= 1) v += __shfl_down(v, off, 64);
            if (lane == 0) out[(size_t)g * N_CLASSES + c] = v + bout[c];
        }
    }
}

// ---------------- launch ----------------

extern "C" void kernel_launch(void* const* d_in, const int* in_sizes, int n_in,
                              void* d_out, int out_size, void* d_ws, size_t ws_size,
                              hipStream_t stream) {
    const int*   node_ids = (const int*)d_in[0];
    const int*   edge_idx = (const int*)d_in[1];   // [2, E] row-major
    const int*   batch    = (const int*)d_in[2];
    const float* emb      = (const float*)d_in[3];
    const float* Wl0      = (const float*)d_in[4];
    const float* bl0      = (const float*)d_in[5];
    const float* Wr0      = (const float*)d_in[6];
    const float* Wl1      = (const float*)d_in[7];
    const float* bl1      = (const float*)d_in[8];
    const float* Wr1      = (const float*)d_in[9];
    const float* Wout     = (const float*)d_in[10];
    const float* bout     = (const float*)d_in[11];
    float* out = (float*)d_out;

    const int* esrc = edge_idx;
    const int* edst = edge_idx + N_EDGES;

    // workspace layout
    __hip_bfloat16* Pb = (__hip_bfloat16*)d_ws;           // N*64 bf16 (6.4 MB)
    float* H = (float*)(Pb + (size_t)N_NODES * 64);       // N*64 f32
    int* row_start     = (int*)(H + (size_t)N_NODES * 64); // N+1
    unsigned short* csr_src = (unsigned short*)(row_start + N_NODES + 1); // E ushort
    int* bhist         = (int*)(csr_src + N_EDGES);       // NB
    int* bucket_start  = bhist + NB_BKT;                  // NB+1
    int* bucket_cursor = bucket_start + NB_BKT + 1;       // NB
    int* gstart        = bucket_cursor + NB_BKT;          // G+1
    // ebuf (E ints = 3.2 MB) aliases Pb (6.4 MB): consumed by k_csr_fill
    // before k_xform writes Pb. Stream-ordered -> safe.
    int* ebuf = (int*)Pb;

    const int BLK = 256;

    hipMemsetAsync(bhist, 0, NB_BKT * sizeof(int), stream);

    // CSR build (reused by both layers)
    k_bhist<<<EB_BLOCKS, BLK, 0, stream>>>(edst, bhist);
    k_bscan<<<1, 512, 0, stream>>>(bhist, bucket_start, bucket_cursor);
    k_bsplit<<<EB_BLOCKS, BLK, 0, stream>>>(esrc, edst, bucket_cursor, ebuf);
    k_csr_fill<<<NB_BKT, BLK, 0, stream>>>(bucket_start, ebuf, row_start, csr_src);
    k_gstart<<<(N_NODES + BLK - 1) / BLK, BLK, 0, stream>>>(batch, gstart);

    const int XFORM_BLOCKS = (N_NODES + 63) / 64;
    const int AGG_BLOCKS   = (N_NODES * 8 + BLK - 1) / BLK;

    // layer 0 (embedding gather fused into xform staging)
    k_xform<<<XFORM_BLOCKS, BLK, 0, stream>>>(node_ids, emb, Wl0, bl0, Wr0, Pb, H);
    k_aggregate<<<AGG_BLOCKS, BLK, 0, stream>>>(row_start, csr_src, Pb, H);

    // layer 1
    k_xform<<<XFORM_BLOCKS, BLK, 0, stream>>>(nullptr, H, Wl1, bl1, Wr1, Pb, H);
    k_aggregate<<<AGG_BLOCKS, BLK, 0, stream>>>(row_start, csr_src, Pb, H);

    // pool + output
    k_pool_out<<<N_GRAPHS, BLK, 0, stream>>>(gstart, H, Wout, bout, out);
}